// Round 1
// baseline (2816.734 us; speedup 1.0000x reference)
//
#include <hip/hip_runtime.h>
#include <hip/hip_bf16.h>

// Problem constants
#define BATCH 4096
#define TSTEPS 80
#define VOCAB 10000
#define EDIM 100
#define EPAD 128        // EDIM zero-padded to MFMA K multiple
#define UDIM 1024

typedef _Float16 half8 __attribute__((ext_vector_type(8)));
typedef float float4v __attribute__((ext_vector_type(4)));

// async global->LDS, 16B per lane. LDS dest must be wave-uniform base + lane*16.
__device__ __forceinline__ void load_lds16(const void* g, void* l) {
    __builtin_amdgcn_global_load_lds(
        (const __attribute__((address_space(1))) unsigned int*)g,
        (__attribute__((address_space(3))) unsigned int*)l,
        16, 0, 0);
}

__device__ __forceinline__ float tanh_fast(float x) {
    // tanh(x) = 1 - 2/(exp(2x)+1); exp under/overflow saturates correctly to -1/+1
    return 1.0f - 2.0f / (__expf(2.0f * x) + 1.0f);
}

// Transpose+convert Wh[k][n] f32 -> WhT[n][k] fp16
__global__ __launch_bounds__(256) void convert_wh(const float* __restrict__ Wh,
                                                  _Float16* __restrict__ WhT) {
    int idx = blockIdx.x * 256 + threadIdx.x;        // 0 .. 1M-1
    int k = idx >> 10, n = idx & 1023;
    WhT[n * UDIM + k] = (_Float16)Wh[idx];           // coalesced read, strided write
}

// Transpose+convert+pad Wx[e][u] f32 -> WxT[u][k] fp16, k in [0,128), zero beyond EDIM
__global__ __launch_bounds__(256) void convert_wx(const float* __restrict__ Wx,
                                                  _Float16* __restrict__ WxT) {
    int idx = blockIdx.x * 256 + threadIdx.x;        // 0 .. 1024*128-1
    int n = idx >> 7, k = idx & 127;
    WxT[idx] = (k < EDIM) ? (_Float16)Wx[k * UDIM + n] : (_Float16)0.0f;
}

// One recurrence step: h_out = tanh( emb[inputs[:,t]] @ Wx + b + h_in @ Wh )
// Tile: 128x128 per block, 4 waves of 64x64, MFMA f32_16x16x32_f16, BK=32.
__global__ __launch_bounds__(256) void rnn_step(
        const int* __restrict__ inputs, const float* __restrict__ emb,
        const _Float16* __restrict__ WxT,   // [UDIM][EPAD]  (n-major)
        const _Float16* __restrict__ WhT,   // [UDIM][UDIM]  (n-major)
        const float* __restrict__ bias,     // [UDIM]
        const _Float16* __restrict__ h_in,  // [BATCH][UDIM]
        _Float16* __restrict__ h_out,       // [BATCH][UDIM]
        int t)
{
    __shared__ _Float16 Asm[128 * 32];   // A tile [m][k]
    __shared__ _Float16 Bsm[128 * 32];   // B tile [n][k] (already transposed source)

    const int tid  = threadIdx.x;
    const int lane = tid & 63;
    const int wave = tid >> 6;
    const int wm = (wave >> 1) * 64;
    const int wn = (wave & 1) * 64;
    const int m0 = blockIdx.y * 128;     // batch-tile
    const int n0 = blockIdx.x * 128;     // unit-tile (8 tiles -> maps to XCD id)

    const int lrow = lane & 15;          // fragment row/col index
    const int lq   = lane >> 4;          // quad -> k-subchunk

    float4v acc[4][4] = {};

    // ---------- Segment X: x_t @ Wx  (K = 128, 4 iters), A gathered from emb ----------
    #pragma unroll 1
    for (int it = 0; it < 4; ++it) {
        const int k0 = it * 32;
        // A: gather fp32 emb rows, convert to fp16, write 16B to LDS
        #pragma unroll
        for (int j = 0; j < 2; ++j) {
            const int c = j * 256 + tid;           // chunk 0..511
            const int m = c >> 2, colc = c & 3;
            const int tok = inputs[(m0 + m) * TSTEPS + t];
            const float* src = emb + (size_t)tok * EDIM;
            const int kb = k0 + colc * 8;
            half8 v;
            #pragma unroll
            for (int e = 0; e < 8; ++e) {
                const int k = kb + e;
                v[e] = (k < EDIM) ? (_Float16)src[k] : (_Float16)0.0f;
            }
            *(half8*)&Asm[c * 8] = v;
        }
        // B: WxT tile rows n0..n0+127, cols k0..k0+31
        #pragma unroll
        for (int j = 0; j < 2; ++j) {
            const int c = j * 256 + tid;
            const int n = c >> 2, colc = c & 3;
            load_lds16(WxT + (n0 + n) * EPAD + k0 + colc * 8, &Bsm[c * 8]);
        }
        __syncthreads();
        half8 af[4], bf[4];
        #pragma unroll
        for (int i = 0; i < 4; ++i)
            af[i] = *(const half8*)&Asm[(wm + i * 16 + lrow) * 32 + lq * 8];
        #pragma unroll
        for (int j = 0; j < 4; ++j)
            bf[j] = *(const half8*)&Bsm[(wn + j * 16 + lrow) * 32 + lq * 8];
        #pragma unroll
        for (int i = 0; i < 4; ++i)
            #pragma unroll
            for (int j = 0; j < 4; ++j)
                acc[i][j] = __builtin_amdgcn_mfma_f32_16x16x32_f16(af[i], bf[j], acc[i][j], 0, 0, 0);
        __syncthreads();
    }

    // ---------- Main segment: h_in @ Wh  (K = 1024, 32 iters) ----------
    #pragma unroll 1
    for (int it = 0; it < 32; ++it) {
        const int k0 = it * 32;
        #pragma unroll
        for (int j = 0; j < 2; ++j) {
            const int c = j * 256 + tid;
            const int m = c >> 2, colc = c & 3;
            load_lds16(h_in + (m0 + m) * UDIM + k0 + colc * 8, &Asm[c * 8]);
        }
        #pragma unroll
        for (int j = 0; j < 2; ++j) {
            const int c = j * 256 + tid;
            const int n = c >> 2, colc = c & 3;
            load_lds16(WhT + (n0 + n) * UDIM + k0 + colc * 8, &Bsm[c * 8]);
        }
        __syncthreads();
        half8 af[4], bf[4];
        #pragma unroll
        for (int i = 0; i < 4; ++i)
            af[i] = *(const half8*)&Asm[(wm + i * 16 + lrow) * 32 + lq * 8];
        #pragma unroll
        for (int j = 0; j < 4; ++j)
            bf[j] = *(const half8*)&Bsm[(wn + j * 16 + lrow) * 32 + lq * 8];
        #pragma unroll
        for (int i = 0; i < 4; ++i)
            #pragma unroll
            for (int j = 0; j < 4; ++j)
                acc[i][j] = __builtin_amdgcn_mfma_f32_16x16x32_f16(af[i], bf[j], acc[i][j], 0, 0, 0);
        __syncthreads();
    }

    // ---------- Epilogue: bias + tanh, store fp16 ----------
    float bj[4];
    #pragma unroll
    for (int j = 0; j < 4; ++j)
        bj[j] = bias[n0 + wn + j * 16 + lrow];
    #pragma unroll
    for (int i = 0; i < 4; ++i) {
        #pragma unroll
        for (int j = 0; j < 4; ++j) {
            const int col = n0 + wn + j * 16 + lrow;
            #pragma unroll
            for (int r = 0; r < 4; ++r) {
                const int row = m0 + wm + i * 16 + lq * 4 + r;
                float v = acc[i][j][r] + bj[j];
                h_out[(size_t)row * UDIM + col] = (_Float16)tanh_fast(v);
            }
        }
    }
}

// out[b] = h[b,:] . Wo + bo   (one wave per row)
__global__ __launch_bounds__(256) void out_proj(const _Float16* __restrict__ h,
                                                const float* __restrict__ Wo,
                                                const float* __restrict__ bo,
                                                float* __restrict__ out) {
    const int lane = threadIdx.x & 63;
    const int wave = threadIdx.x >> 6;
    const int row = blockIdx.x * 4 + wave;
    const _Float16* hr = h + (size_t)row * UDIM;
    float s = 0.0f;
    #pragma unroll
    for (int i = 0; i < 16; ++i) {
        const int k = lane + i * 64;
        s += (float)hr[k] * Wo[k];
    }
    #pragma unroll
    for (int off = 32; off > 0; off >>= 1) s += __shfl_down(s, off, 64);
    if (lane == 0) out[row] = s + bo[0];
}

extern "C" void kernel_launch(void* const* d_in, const int* in_sizes, int n_in,
                              void* d_out, int out_size, void* d_ws, size_t ws_size,
                              hipStream_t stream) {
    const int*   inputs = (const int*)  d_in[0];   // [B,T]
    const float* emb    = (const float*)d_in[1];   // [V,E]
    const float* Wx     = (const float*)d_in[2];   // [E,U]
    const float* Wh     = (const float*)d_in[3];   // [U,U]
    const float* b      = (const float*)d_in[4];   // [U]
    const float* Wo     = (const float*)d_in[5];   // [U,1]
    const float* bo     = (const float*)d_in[6];   // [1]
    float* out = (float*)d_out;

    char* ws = (char*)d_ws;
    _Float16* WhT = (_Float16*)ws;                               // 2 MB
    _Float16* WxT = (_Float16*)(ws + (2u << 20));                // 256 KB
    _Float16* hA  = (_Float16*)(ws + (2u << 20) + (256u << 10)); // 8 MB
    _Float16* hB  = hA + (size_t)BATCH * UDIM;                   // 8 MB

    convert_wh<<<dim3(4096), dim3(256), 0, stream>>>(Wh, WhT);
    convert_wx<<<dim3(512),  dim3(256), 0, stream>>>(Wx, WxT);
    hipMemsetAsync(hA, 0, (size_t)BATCH * UDIM * sizeof(_Float16), stream);

    for (int t = 0; t < TSTEPS; ++t) {
        const _Float16* hin = (t & 1) ? hB : hA;
        _Float16*       hout = (t & 1) ? hA : hB;
        rnn_step<<<dim3(8, 32), dim3(256), 0, stream>>>(inputs, emb, WxT, WhT, b, hin, hout, t);
    }
    // T=80 even -> final h is in hA
    out_proj<<<dim3(1024), dim3(256), 0, stream>>>(hA, Wo, bo, out);
}

// Round 2
// 2077.843 us; speedup vs baseline: 1.3556x; 1.3556x over previous
//
#include <hip/hip_runtime.h>
#include <hip/hip_bf16.h>

// Problem constants
#define BATCH 4096
#define TSTEPS 80
#define VOCAB 10000
#define EDIM 100
#define EPAD 128        // EDIM zero-padded to MFMA K multiple
#define UDIM 1024

typedef _Float16 half8 __attribute__((ext_vector_type(8)));
typedef float float4v __attribute__((ext_vector_type(4)));

// async global->LDS, 16B per lane. LDS dest must be wave-uniform base + lane*16.
__device__ __forceinline__ void load_lds16(const void* g, void* l) {
    __builtin_amdgcn_global_load_lds(
        (const __attribute__((address_space(1))) unsigned int*)g,
        (__attribute__((address_space(3))) unsigned int*)l,
        16, 0, 0);
}

__device__ __forceinline__ float tanh_fast(float x) {
    // tanh(x) = 1 - 2/(exp(2x)+1); exp under/overflow saturates to +-1
    return 1.0f - 2.0f / (__expf(2.0f * x) + 1.0f);
}

// Transpose+convert Wh[k][n] f32 -> WhT[n][k] fp16
__global__ __launch_bounds__(256) void convert_wh(const float* __restrict__ Wh,
                                                  _Float16* __restrict__ WhT) {
    int idx = blockIdx.x * 256 + threadIdx.x;        // 0 .. 1M-1
    int k = idx >> 10, n = idx & 1023;
    WhT[n * UDIM + k] = (_Float16)Wh[idx];
}

// Transpose+convert+pad Wx[e][u] f32 -> WxT[u][k] fp16, k in [0,128)
__global__ __launch_bounds__(256) void convert_wx(const float* __restrict__ Wx,
                                                  _Float16* __restrict__ WxT) {
    int idx = blockIdx.x * 256 + threadIdx.x;        // 0 .. 1024*128-1
    int n = idx >> 7, k = idx & 127;
    WxT[idx] = (k < EDIM) ? (_Float16)Wx[k * UDIM + n] : (_Float16)0.0f;
}

// One-time embedding gather: xemb[t][m][0:128] = pad(emb[inputs[m][t]])
__global__ __launch_bounds__(256) void embed_gather(
        const int* __restrict__ inputs, const float* __restrict__ emb,
        _Float16* __restrict__ xemb) {
    int c = blockIdx.x * 256 + threadIdx.x;    // one 8-half chunk; 80*4096*16 total
    int kc = c & 15;
    int m  = (c >> 4) & 4095;
    int t  = c >> 16;
    int tok = inputs[m * TSTEPS + t];
    const float* src = emb + (size_t)tok * EDIM + kc * 8;
    half8 v;
    #pragma unroll
    for (int e = 0; e < 8; ++e) {
        int k = kc * 8 + e;
        v[e] = (k < EDIM) ? (_Float16)src[e] : (_Float16)0.0f;
    }
    *(half8*)&xemb[(size_t)c * 8] = v;
}

// One recurrence step: h_out = tanh( xemb_t @ Wx^T-layout + b + h_in @ Wh )
// Block tile 64(M)x128(N), grid (8,64)=512 blocks (2/CU), 4 waves of 32x64.
// Double-buffered LDS, BK=32, K = 128 (x-segment) + 1024 (h-segment) = 36 iters.
__global__ __launch_bounds__(256, 2) void rnn_step(
        const _Float16* __restrict__ xt,    // xemb + t*B*128: [BATCH][EPAD]
        const _Float16* __restrict__ WxT,   // [UDIM][EPAD]
        const _Float16* __restrict__ WhT,   // [UDIM][UDIM]
        const float* __restrict__ bias,     // [UDIM]
        const _Float16* __restrict__ h_in,  // [BATCH][UDIM]
        _Float16* __restrict__ h_out)       // [BATCH][UDIM]
{
    __shared__ _Float16 smem[12288];        // 24 KB
    _Float16* Abuf = smem;                  // 2 x 2048 halfs (64x32 tile each)
    _Float16* Bbuf = smem + 4096;           // 2 x 4096 halfs (128x32 tile each)
    _Float16* Csm  = smem;                  // epilogue: 64x128 halfs (16 KB)

    const int tid  = threadIdx.x;
    const int lane = tid & 63;
    const int wave = tid >> 6;
    const int wm = (wave >> 1) * 32;        // wave tile 32(M) x 64(N)
    const int wn = (wave & 1) * 64;
    const int m0 = blockIdx.y * 64;
    const int n0 = blockIdx.x * 128;        // bx in [0,8) -> XCD-sliced B reuse

    const int lrow = lane & 15;
    const int lq   = lane >> 4;

    float4v acc[2][4] = {};

    // stage iteration kk into buffer buf
    auto stage = [&](int kk, int buf) {
        const _Float16 *asrc, *bsrc;
        int astr, bstr;
        if (kk < 4) {           // x-segment
            asrc = xt  + (size_t)m0 * EPAD + kk * 32;  astr = EPAD;
            bsrc = WxT + (size_t)n0 * EPAD + kk * 32;  bstr = EPAD;
        } else {                // h-segment
            const int k0 = kk * 32 - EPAD;
            asrc = h_in + (size_t)m0 * UDIM + k0;      astr = UDIM;
            bsrc = WhT  + (size_t)n0 * UDIM + k0;      bstr = UDIM;
        }
        { // A: 64x32 = 256 chunks, 1 per thread
            int m = tid >> 2, kc = tid & 3;
            load_lds16(asrc + m * astr + kc * 8, Abuf + buf * 2048 + tid * 8);
        }
        #pragma unroll
        for (int j = 0; j < 2; ++j) {  // B: 128x32 = 512 chunks, 2 per thread
            int c = j * 256 + tid;
            int n = c >> 2, kc = c & 3;
            load_lds16(bsrc + n * bstr + kc * 8, Bbuf + buf * 4096 + c * 8);
        }
    };

    stage(0, 0);
    __syncthreads();   // drain stage(0)

    #pragma unroll 1
    for (int kk = 0; kk < 36; ++kk) {
        const int cur = kk & 1;
        if (kk + 1 < 36) stage(kk + 1, cur ^ 1);   // prefetch; lands during compute

        half8 af[2], bf[4];
        #pragma unroll
        for (int i = 0; i < 2; ++i)
            af[i] = *(const half8*)&Abuf[cur * 2048 + (wm + i * 16 + lrow) * 32 + lq * 8];
        #pragma unroll
        for (int j = 0; j < 4; ++j)
            bf[j] = *(const half8*)&Bbuf[cur * 4096 + (wn + j * 16 + lrow) * 32 + lq * 8];
        #pragma unroll
        for (int i = 0; i < 2; ++i)
            #pragma unroll
            for (int j = 0; j < 4; ++j)
                acc[i][j] = __builtin_amdgcn_mfma_f32_16x16x32_f16(af[i], bf[j], acc[i][j], 0, 0, 0);
        __syncthreads();   // drains prefetch vmcnt + all LDS reads of cur
    }

    // ---- Epilogue: bias + tanh -> LDS transpose -> coalesced 16B stores ----
    float bj[4];
    #pragma unroll
    for (int j = 0; j < 4; ++j)
        bj[j] = bias[n0 + wn + j * 16 + lrow];
    #pragma unroll
    for (int i = 0; i < 2; ++i) {
        #pragma unroll
        for (int j = 0; j < 4; ++j) {
            const int col = wn + j * 16 + lrow;
            #pragma unroll
            for (int r = 0; r < 4; ++r) {
                const int row = wm + i * 16 + lq * 4 + r;
                Csm[row * 128 + col] = (_Float16)tanh_fast(acc[i][j][r] + bj[j]);
            }
        }
    }
    __syncthreads();
    #pragma unroll
    for (int kq = 0; kq < 4; ++kq) {       // 1024 16B-chunks, 4 per thread
        int c = kq * 256 + tid;
        int row = c >> 4, cc = c & 15;
        half8 v = *(const half8*)&Csm[row * 128 + cc * 8];
        *(half8*)&h_out[(size_t)(m0 + row) * UDIM + n0 + cc * 8] = v;
    }
}

// out[b] = h[b,:] . Wo + bo   (one wave per row)
__global__ __launch_bounds__(256) void out_proj(const _Float16* __restrict__ h,
                                                const float* __restrict__ Wo,
                                                const float* __restrict__ bo,
                                                float* __restrict__ out) {
    const int lane = threadIdx.x & 63;
    const int wave = threadIdx.x >> 6;
    const int row = blockIdx.x * 4 + wave;
    const _Float16* hr = h + (size_t)row * UDIM;
    float s = 0.0f;
    #pragma unroll
    for (int i = 0; i < 16; ++i) {
        const int k = lane + i * 64;
        s += (float)hr[k] * Wo[k];
    }
    #pragma unroll
    for (int off = 32; off > 0; off >>= 1) s += __shfl_down(s, off, 64);
    if (lane == 0) out[row] = s + bo[0];
}

extern "C" void kernel_launch(void* const* d_in, const int* in_sizes, int n_in,
                              void* d_out, int out_size, void* d_ws, size_t ws_size,
                              hipStream_t stream) {
    const int*   inputs = (const int*)  d_in[0];   // [B,T]
    const float* emb    = (const float*)d_in[1];   // [V,E]
    const float* Wx     = (const float*)d_in[2];   // [E,U]
    const float* Wh     = (const float*)d_in[3];   // [U,U]
    const float* b      = (const float*)d_in[4];   // [U]
    const float* Wo     = (const float*)d_in[5];   // [U,1]
    const float* bo     = (const float*)d_in[6];   // [1]
    float* out = (float*)d_out;

    char* ws = (char*)d_ws;
    _Float16* WhT  = (_Float16*)ws;                                // 2 MB
    _Float16* WxT  = (_Float16*)(ws + (2u << 20));                 // 256 KB
    _Float16* hA   = (_Float16*)(ws + (2u << 20) + (256u << 10));  // 8 MB
    _Float16* hB   = hA + (size_t)BATCH * UDIM;                    // 8 MB
    _Float16* xemb = hB + (size_t)BATCH * UDIM;                    // 80*4096*128*2 = 84 MB

    convert_wh<<<dim3(4096), dim3(256), 0, stream>>>(Wh, WhT);
    convert_wx<<<dim3(512),  dim3(256), 0, stream>>>(Wx, WxT);
    embed_gather<<<dim3(20480), dim3(256), 0, stream>>>(inputs, emb, xemb);
    hipMemsetAsync(hA, 0, (size_t)BATCH * UDIM * sizeof(_Float16), stream);

    for (int t = 0; t < TSTEPS; ++t) {
        const _Float16* hin  = (t & 1) ? hB : hA;
        _Float16*       hout = (t & 1) ? hA : hB;
        rnn_step<<<dim3(8, 64), dim3(256), 0, stream>>>(
            xemb + (size_t)t * BATCH * EPAD, WxT, WhT, b, hin, hout);
    }
    // T=80 even -> final h in hA
    out_proj<<<dim3(1024), dim3(256), 0, stream>>>(hA, Wo, bo, out);
}